// Round 4
// baseline (169.306 us; speedup 1.0000x reference)
//
#include <hip/hip_runtime.h>
#include <hip/hip_bf16.h>

#define MARGIN 0.85f

// ============ Phase 1: Q[m] = H0*H1*...*H30 for m in [0, 2R) ============
// m < R: head side rid=m;  m >= R: tail side rid=m-R.
// One half-wave (32 lanes) per matrix; lane j holds row j of C in registers.
// Output layout: qout_all[m*992 + row*32 + col], col 31 padded with 0.
__global__ __launch_bounds__(256) void build_q_kernel(
    const float* __restrict__ head_rot_w,
    const float* __restrict__ tail_rot_w,
    float* __restrict__ qout_all, int R)
{
    __shared__ __align__(16) float ww[8 * 992];
    const int tid = threadIdx.x;
    const int g = tid >> 5;       // half-wave group 0..7 (one matrix each)
    const int j = tid & 31;       // row index within matrix
    const int m = blockIdx.x * 8 + g;
    const bool act = (m < 2 * R);
    const int side = act ? (m >= R ? 1 : 0) : 0;
    const int rid  = act ? (side ? m - R : m) : 0;

    // zero-init so pad column 31 stays 0
    for (int e = tid; e < 8 * 992; e += 256) ww[e] = 0.0f;
    __syncthreads();

    if (act) {
        const float* rw = (side ? tail_rot_w : head_rot_w) + (size_t)rid * 961;
        for (int e = j; e < 961; e += 32) {
            float xv = rw[e];
            // exact gelu: x * 0.5 * (1 + erf(x/sqrt(2)))
            float gv = 0.5f * xv * (1.0f + erff(xv * 0.7071067811865475f));
            int row = e / 31;
            int col = e - row * 31;
            ww[g * 992 + row * 32 + col] = gv;
        }
    }
    __syncthreads();

    float c[32];
    #pragma unroll
    for (int k = 0; k < 32; ++k) c[k] = (k == j) ? 1.0f : 0.0f;

    const float* wbase = &ww[g * 992];
    #pragma unroll 1
    for (int i = 0; i < 31; ++i) {
        const float* wi = wbase + i * 32;
        float w[32];
        float4 y4 = make_float4(0.f, 0.f, 0.f, 0.f);
        float4 n4 = make_float4(0.f, 0.f, 0.f, 0.f);
        #pragma unroll
        for (int c4 = 0; c4 < 8; ++c4) {
            float4 w4 = *reinterpret_cast<const float4*>(wi + c4 * 4);
            w[c4*4+0] = w4.x; w[c4*4+1] = w4.y; w[c4*4+2] = w4.z; w[c4*4+3] = w4.w;
            y4.x = fmaf(c[c4*4+0], w4.x, y4.x);
            y4.y = fmaf(c[c4*4+1], w4.y, y4.y);
            y4.z = fmaf(c[c4*4+2], w4.z, y4.z);
            y4.w = fmaf(c[c4*4+3], w4.w, y4.w);
            n4.x = fmaf(w4.x, w4.x, n4.x);
            n4.y = fmaf(w4.y, w4.y, n4.y);
            n4.z = fmaf(w4.z, w4.z, n4.z);
            n4.w = fmaf(w4.w, w4.w, n4.w);
        }
        float y = (y4.x + y4.y) + (y4.z + y4.w);   // (C w)_j
        float n = (n4.x + n4.y) + (n4.z + n4.w);   // ||w||^2 (no eps, matches ref)
        float sy = (2.0f / n) * y;
        #pragma unroll
        for (int k = 0; k < 32; ++k) c[k] = fmaf(-sy, w[k], c[k]);
    }

    if (act && j < 31) {
        float* qo = qout_all + (size_t)m * 992 + j * 32;
        #pragma unroll
        for (int c4 = 0; c4 < 8; ++c4) {
            *reinterpret_cast<float4*>(qo + c4 * 4) =
                make_float4(c[c4*4+0], c[c4*4+1], c[c4*4+2], c[c4*4+3]);
        }
    }
}

// ============ Phase 1.5: th[b][32] = boost(rotate(emb[u[b]])) ============
// One block of 64 per b. Lane c computes rotated component c.
__global__ __launch_bounds__(64) void head_kernel(
    const int* __restrict__ u_idx, const int* __restrict__ r_idx,
    const float* __restrict__ emb,
    const float* __restrict__ head_boost_w,
    const float* __restrict__ q_all, float* __restrict__ th_out)
{
    const int b = blockIdx.x;
    const int lane = threadIdx.x;
    const int r = __builtin_amdgcn_readfirstlane(r_idx[b]);
    const int ub = __builtin_amdgcn_readfirstlane(u_idx[b]);

    __shared__ float q[992];
    __shared__ float h[32];
    __shared__ float ro[32];
    __shared__ float tmp[32];

    const float* qsrc = q_all + (size_t)r * 992;   // head side: m = r
    for (int e = lane; e < 992; e += 64) q[e] = qsrc[e];
    if (lane < 32) {
        h[lane] = emb[(size_t)ub * 32 + lane];
        float rv = 0.0f;
        if (lane < 31)
            rv = tanhf(head_boost_w[(size_t)r * 31 + lane]) * 0.03125f;
        ro[lane] = rv;
        tmp[lane] = 0.0f;
    }
    __syncthreads();

    float hr = 0.0f;
    if (lane < 31) {
        #pragma unroll 1
        for (int d = 0; d < 31; ++d) hr = fmaf(h[1 + d], q[d * 32 + lane], hr);
        tmp[lane] = hr * ro[lane];
    }
    __syncthreads();

    float v2 = 0.0f, dot = 0.0f;
    #pragma unroll 1
    for (int k = 0; k < 31; ++k) { v2 = fmaf(ro[k], ro[k], v2); dot += tmp[k]; }
    float zeta = 1.0f / (sqrtf(1.0f - v2) + 1e-8f);
    float coef = (zeta - 1.0f) / (v2 + 1e-9f);
    float h0 = h[0];
    if (lane == 0)  th_out[(size_t)b * 32 + 0] = zeta * (h0 - dot);
    if (lane < 31)  th_out[(size_t)b * 32 + 1 + lane] =
                        fmaf(ro[lane], coef * dot - zeta * h0, hr);
}

// ============ Phase 2: per (b, n) tail transform + score ============
// Q rows are block-uniform -> read with uniform addresses so the compiler
// emits s_load into SGPRs (scalar pipe), keeping the rotation loop pure
// v_fma with one SGPR operand. No LDS staging of Q.
__global__ __launch_bounds__(256) void tail_kernel(
    const int* __restrict__ u_idx, const int* __restrict__ r_idx,
    const int* __restrict__ v_idx,
    const float* __restrict__ emb,
    const float* __restrict__ bias_head,
    const float* __restrict__ bias_tail,
    const float* __restrict__ tail_boost_w,
    const float* __restrict__ q_all, const float* __restrict__ th_in,
    float* __restrict__ out, int R)
{
    const int b = blockIdx.x;
    const int tid = threadIdx.x;
    const int r = __builtin_amdgcn_readfirstlane(r_idx[b]);

    __shared__ __align__(16) float ro[32];
    __shared__ float th[32];
    __shared__ float sc[3];  // zeta, coef, tanh(bias_head[u])

    if (tid < 32) {
        float rv = 0.0f;
        if (tid < 31)
            rv = tanhf(tail_boost_w[(size_t)r * 31 + tid]) * 0.03125f;
        ro[tid] = rv;
    } else if (tid < 64) {
        th[tid - 32] = th_in[(size_t)b * 32 + (tid - 32)];
    }
    __syncthreads();
    if (tid == 0) {
        float v2 = 0.0f;
        #pragma unroll
        for (int k = 0; k < 31; ++k) v2 = fmaf(ro[k], ro[k], v2);
        float zeta = 1.0f / (sqrtf(1.0f - v2) + 1e-8f);
        sc[0] = zeta;
        sc[1] = (zeta - 1.0f) / (v2 + 1e-9f);
        sc[2] = tanhf(bias_head[u_idx[b]]);
    }
    __syncthreads();

    const int vi = v_idx[(size_t)b * 256 + tid];
    const float btl = bias_tail[vi];

    // load emb row: 32 fp32 = 128 B contiguous per thread
    float x[32];
    const float4* ep = reinterpret_cast<const float4*>(emb + (size_t)vi * 32);
    #pragma unroll
    for (int qq = 0; qq < 8; ++qq) {
        float4 e4 = ep[qq];
        x[qq*4+0] = e4.x; x[qq*4+1] = e4.y; x[qq*4+2] = e4.z; x[qq*4+3] = e4.w;
    }

    // rotation: acc[c] = sum_d x[1+d] * Q[d][c]  (col 31 is zero pad)
    // qsrc addresses are uniform (no tid dependence) -> scalar loads.
    const float* qsrc = q_all + ((size_t)R + (size_t)r) * 992;  // tail side
    float acc[32];
    #pragma unroll
    for (int c = 0; c < 32; ++c) acc[c] = 0.0f;
    #pragma unroll 1
    for (int d = 0; d < 31; ++d) {
        const float xd = x[1 + d];
        const float* qr = qsrc + d * 32;
        #pragma unroll
        for (int c = 0; c < 32; ++c) {
            acc[c] = fmaf(xd, qr[c], acc[c]);
        }
    }

    const float zeta = sc[0], coef = sc[1], tbh = sc[2];
    const float t0 = x[0];

    float dot = 0.0f;
    #pragma unroll
    for (int c = 0; c < 31; ++c) dot = fmaf(acc[c], ro[c], dot);

    float d0 = zeta * (t0 - dot) - th[0];
    float mkv = -d0 * d0;                 // sum d^2 - 2*d0^2
    const float cz = coef * dot - zeta * t0;
    #pragma unroll
    for (int c = 0; c < 31; ++c) {
        float dc = fmaf(ro[c], cz, acc[c]) - th[1 + c];
        mkv = fmaf(dc, dc, mkv);
    }
    float res = MARGIN - mkv + tbh + tanhf(btl);
    out[(size_t)b * 256 + tid] = res;
}

extern "C" void kernel_launch(void* const* d_in, const int* in_sizes, int n_in,
                              void* d_out, int out_size, void* d_ws, size_t ws_size,
                              hipStream_t stream) {
    (void)n_in; (void)out_size; (void)ws_size;
    const int* u  = (const int*)d_in[0];
    const int* r  = (const int*)d_in[1];
    const int* v  = (const int*)d_in[2];
    const float* emb = (const float*)d_in[3];
    const float* bh  = (const float*)d_in[4];
    const float* bt  = (const float*)d_in[5];
    const float* hrw = (const float*)d_in[6];
    const float* hbw = (const float*)d_in[7];
    const float* trw = (const float*)d_in[8];
    const float* tbw = (const float*)d_in[9];

    const int B = in_sizes[0];                 // 1024
    const int R = in_sizes[7] / 31;            // 2000

    float* qall = (float*)d_ws;                      // [2R][992] fp32
    float* th   = qall + (size_t)2 * R * 992;        // [B][32] fp32

    const int nmat_blocks = (2 * R + 7) / 8;
    build_q_kernel<<<nmat_blocks, 256, 0, stream>>>(hrw, trw, qall, R);
    head_kernel<<<B, 64, 0, stream>>>(u, r, emb, hbw, qall, th);
    tail_kernel<<<B, 256, 0, stream>>>(u, r, v, emb, bh, bt, tbw, qall, th,
                                       (float*)d_out, R);
}

// Round 5
// 149.083 us; speedup vs baseline: 1.1356x; 1.1356x over previous
//
#include <hip/hip_runtime.h>
#include <hip/hip_bf16.h>

#define MARGIN 0.85f

// ============ Fused per-b kernel ============
// One wave (64 threads) per b. Half-wave g (32 lanes) builds the 31x31
// Householder product Q_g (g=0 head, g=1 tail) with lane j holding row j
// in registers. Then:
//   th   = B_head(Q_head-rotate(emb[u]))        (exactly as reference)
//   y    = 2 * B_tail * (G * th),  G = diag(-1, 1...1)
//   w_sp = Q_tail * y_sp   (from half-1's registers: lane j has row j)
//   beta = th^T G th;  const_b = MARGIN - beta + tanh(bias_head[u])
// Identity used downstream: mkv = t^T G t - w.t + beta (M Lorentz-preserves G;
// the ref's 1e-8/1e-9 eps perturb this by O(1e-7) -- negligible).
__global__ __launch_bounds__(64) void per_b_kernel(
    const int* __restrict__ u_idx, const int* __restrict__ r_idx,
    const float* __restrict__ emb,
    const float* __restrict__ bias_head,
    const float* __restrict__ head_rot_w,
    const float* __restrict__ head_boost_w,
    const float* __restrict__ tail_rot_w,
    const float* __restrict__ tail_boost_w,
    float* __restrict__ wv)
{
    __shared__ __align__(16) float ww[2 * 992];  // gelu'd w vectors, col31=0
    __shared__ __align__(16) float qh[992];      // Q_head rows 0..30, pitch 32
    __shared__ float hs[32], roh[32], rot[32], th[32], yv[32], tmp[32];

    const int lane = threadIdx.x;
    const int g = lane >> 5;        // 0 = head matrix, 1 = tail matrix
    const int j = lane & 31;        // row index
    const int b = blockIdx.x;
    const int r  = __builtin_amdgcn_readfirstlane(r_idx[b]);
    const int ub = __builtin_amdgcn_readfirstlane(u_idx[b]);

    for (int e = lane; e < 2 * 992; e += 64) ww[e] = 0.0f;
    if (lane < 32) hs[lane] = emb[(size_t)ub * 32 + lane];
    if (g == 0) roh[j] = (j < 31) ? tanhf(head_boost_w[(size_t)r * 31 + j]) * 0.03125f : 0.0f;
    else        rot[j] = (j < 31) ? tanhf(tail_boost_w[(size_t)r * 31 + j]) * 0.03125f : 0.0f;
    __syncthreads();

    {
        const float* rw = (g ? tail_rot_w : head_rot_w) + (size_t)r * 961;
        for (int e = j; e < 961; e += 32) {
            float xv = rw[e];
            float gv = 0.5f * xv * (1.0f + erff(xv * 0.7071067811865475f));
            int row = e / 31;
            int col = e - row * 31;
            ww[g * 992 + row * 32 + col] = gv;
        }
    }
    __syncthreads();

    // Build C = H0*H1*...*H30, row j in registers.
    float c[32];
    #pragma unroll
    for (int k = 0; k < 32; ++k) c[k] = (k == j) ? 1.0f : 0.0f;

    const float* wbase = &ww[g * 992];
    #pragma unroll 1
    for (int i = 0; i < 31; ++i) {
        const float* wi = wbase + i * 32;
        float w[32];
        float4 y4 = make_float4(0.f, 0.f, 0.f, 0.f);
        float4 n4 = make_float4(0.f, 0.f, 0.f, 0.f);
        #pragma unroll
        for (int c4 = 0; c4 < 8; ++c4) {
            float4 w4 = *reinterpret_cast<const float4*>(wi + c4 * 4);
            w[c4*4+0] = w4.x; w[c4*4+1] = w4.y; w[c4*4+2] = w4.z; w[c4*4+3] = w4.w;
            y4.x = fmaf(c[c4*4+0], w4.x, y4.x);
            y4.y = fmaf(c[c4*4+1], w4.y, y4.y);
            y4.z = fmaf(c[c4*4+2], w4.z, y4.z);
            y4.w = fmaf(c[c4*4+3], w4.w, y4.w);
            n4.x = fmaf(w4.x, w4.x, n4.x);
            n4.y = fmaf(w4.y, w4.y, n4.y);
            n4.z = fmaf(w4.z, w4.z, n4.z);
            n4.w = fmaf(w4.w, w4.w, n4.w);
        }
        float y = (y4.x + y4.y) + (y4.z + y4.w);
        float n = (n4.x + n4.y) + (n4.z + n4.w);
        float sy = (2.0f / n) * y;
        #pragma unroll
        for (int k = 0; k < 32; ++k) c[k] = fmaf(-sy, w[k], c[k]);
    }
    __syncthreads();

    // Stage Q_head to LDS (half 1 keeps Q_tail rows in registers).
    if (g == 0 && j < 31) {
        #pragma unroll
        for (int c4 = 0; c4 < 8; ++c4)
            *reinterpret_cast<float4*>(&qh[j * 32 + c4 * 4]) =
                make_float4(c[c4*4+0], c[c4*4+1], c[c4*4+2], c[c4*4+3]);
    }
    __syncthreads();

    // Phase A: rotate head then boost -> th (exactly the ref formulas).
    float hr = 0.0f;
    if (j < 31) {
        #pragma unroll 1
        for (int d = 0; d < 31; ++d) hr = fmaf(hs[1 + d], qh[d * 32 + j], hr);
    }
    if (g == 0) tmp[j] = (j < 31) ? hr * roh[j] : 0.0f;
    __syncthreads();

    float v2h = 0.0f, doth = 0.0f;
    #pragma unroll 1
    for (int k = 0; k < 31; ++k) { v2h = fmaf(roh[k], roh[k], v2h); doth += tmp[k]; }
    const float zh = 1.0f / (sqrtf(1.0f - v2h) + 1e-8f);
    const float ch = (zh - 1.0f) / (v2h + 1e-9f);
    const float h0 = hs[0];
    if (g == 0) {
        if (j < 31) th[1 + j] = fmaf(roh[j], ch * doth - zh * h0, hr);
        else        th[0] = zh * (h0 - doth);
    }
    __syncthreads();

    // Phase B: y = 2 * B_tail * (G th).
    float v2t = 0.0f, dots = 0.0f;
    #pragma unroll 1
    for (int k = 0; k < 31; ++k) {
        v2t = fmaf(rot[k], rot[k], v2t);
        dots = fmaf(rot[k], th[1 + k], dots);
    }
    const float zt = 1.0f / (sqrtf(1.0f - v2t) + 1e-8f);
    const float ct = (zt - 1.0f) / (v2t + 1e-9f);
    const float th0 = th[0];
    if (g == 0) {
        if (j < 31) yv[1 + j] = 2.0f * fmaf(fmaf(zt, th0, ct * dots), rot[j], th[1 + j]);
        else        yv[0] = 2.0f * zt * (-th0 - dots);
    }
    __syncthreads();

    // Phase C: w_sp = Q_tail * y_sp from half-1 registers; scalars from lane 0.
    float* wout = wv + (size_t)b * 34;
    if (g == 1 && j < 31) {
        float wsp = 0.0f;
        #pragma unroll 1
        for (int k = 0; k < 31; ++k) wsp = fmaf(c[k], yv[1 + k], wsp);
        wout[1 + j] = wsp;
    }
    if (lane == 0) {
        wout[0] = yv[0];
        float beta = -th0 * th0;
        #pragma unroll 1
        for (int k = 0; k < 31; ++k) beta = fmaf(th[1 + k], th[1 + k], beta);
        wout[32] = MARGIN - beta + tanhf(bias_head[ub]);
        wout[33] = 0.0f;
    }
}

// ============ Score kernel ============
// score(b,n) = const_b + w_b . t - (sum t^2 - 2 t0^2) + tanh(bias_tail[v])
__global__ __launch_bounds__(256) void score_kernel(
    const int* __restrict__ v_idx,
    const float* __restrict__ emb,
    const float* __restrict__ bias_tail,
    const float* __restrict__ wv,
    float* __restrict__ out)
{
    const int b = blockIdx.x;
    const int tid = threadIdx.x;
    __shared__ __align__(16) float wl[36];
    if (tid < 33) wl[tid] = wv[(size_t)b * 34 + tid];
    else if (tid < 36) wl[tid] = 0.0f;
    __syncthreads();

    const int vi = v_idx[(size_t)b * 256 + tid];
    const float btl = bias_tail[vi];
    const float4* ep = reinterpret_cast<const float4*>(emb + (size_t)vi * 32);

    float dotw = 0.0f, qsum = 0.0f, t0 = 0.0f;
    #pragma unroll
    for (int qq = 0; qq < 8; ++qq) {
        float4 e4 = ep[qq];
        float4 w4 = *reinterpret_cast<const float4*>(&wl[qq * 4]);
        if (qq == 0) t0 = e4.x;
        dotw = fmaf(e4.x, w4.x, dotw);
        dotw = fmaf(e4.y, w4.y, dotw);
        dotw = fmaf(e4.z, w4.z, dotw);
        dotw = fmaf(e4.w, w4.w, dotw);
        qsum = fmaf(e4.x, e4.x, qsum);
        qsum = fmaf(e4.y, e4.y, qsum);
        qsum = fmaf(e4.z, e4.z, qsum);
        qsum = fmaf(e4.w, e4.w, qsum);
    }
    float score = wl[32] + dotw - qsum + 2.0f * t0 * t0 + tanhf(btl);
    out[(size_t)b * 256 + tid] = score;
}

extern "C" void kernel_launch(void* const* d_in, const int* in_sizes, int n_in,
                              void* d_out, int out_size, void* d_ws, size_t ws_size,
                              hipStream_t stream) {
    (void)n_in; (void)out_size; (void)ws_size;
    const int* u  = (const int*)d_in[0];
    const int* r  = (const int*)d_in[1];
    const int* v  = (const int*)d_in[2];
    const float* emb = (const float*)d_in[3];
    const float* bh  = (const float*)d_in[4];
    const float* bt  = (const float*)d_in[5];
    const float* hrw = (const float*)d_in[6];
    const float* hbw = (const float*)d_in[7];
    const float* trw = (const float*)d_in[8];
    const float* tbw = (const float*)d_in[9];

    const int B = in_sizes[0];                 // 1024

    float* wv = (float*)d_ws;                  // [B][34] fp32 (w[32], const, pad)

    per_b_kernel<<<B, 64, 0, stream>>>(u, r, emb, bh, hrw, hbw, trw, tbw, wv);
    score_kernel<<<B, 256, 0, stream>>>(v, emb, bt, wv, (float*)d_out);
}